// Round 6
// baseline (286.309 us; speedup 1.0000x reference)
//
#include <hip/hip_runtime.h>
#include <math.h>

// Problem constants (match reference file)
#define NB 16
#define NPIX 1048576                       // 1024*1024
#define BINS 4096
#define HBINS (BINS / 2)                   // packed u16-pair words: 2048
#define DUMMY_W HBINS                      // dead word for fg lanes (branchless atomic)
#define CHUNKS 64                          // blocks per sample in pass A
#define TPB_A 256
#define PIX_PER_BLOCK (NPIX / CHUNKS)      // 16384
#define PPT 4                              // pixels per thread per iter (one float4/stream)
#define ITERS_A (PIX_PER_BLOCK / (TPB_A * PPT))   // 16
#define TPB_B 256
#define BINS_PER_CHUNK (BINS / TPB_B)      // 16 bins per pass_b thread
#define WORDS_PER_THREAD (HBINS / TPB_B)   // 8 packed words per pass_b thread
#define BLOSS_MAX 16.2f
#define BINW (BLOSS_MAX / (float)BINS)
#define B_CAP 15.9424f                     // -log(1-(1-1e-7f)) in f32 = -log(2*2^-24)
#define F_CAP 16.1181f                     // -log(1e-7f)

typedef float f32x4 __attribute__((ext_vector_type(4)));

// Pass A (round-3 config, known 81us). Template NOATOMIC=true is a DIAGNOSTIC
// instantiation: identical code but the LDS atomic is replaced by an asm
// keep-alive sink (no DCE). It runs AFTER pass_c on already-consumed buffers,
// so correctness is unaffected; its duration isolates the scattered-LDS-atomic
// cost, which is the last unmeasured candidate for the ~140K missing cy/CU.
template<bool NOATOMIC>
__global__ __launch_bounds__(TPB_A, 8) void pass_a_t(
    const float* __restrict__ probs, const float* __restrict__ gt,
    unsigned* __restrict__ g_hist, float* __restrict__ f_part,
    float* __restrict__ b_part)
{
    __shared__ unsigned s_cnt[HBINS + 8];     // packed 2x u16 counts + dummy pad
    __shared__ float s_redf[TPB_A / 64];
    __shared__ float s_redb[TPB_A / 64];

    const int tid = threadIdx.x;
    for (int j = tid; j < HBINS + 8; j += TPB_A) s_cnt[j] = 0u;
    __syncthreads();

    const int blk = blockIdx.x;
    const int b = blk / CHUNKS;
    const int chunk = blk % CHUNKS;
    const float* p0 = probs + (size_t)b * 2 * NPIX;
    const float* p1 = p0 + NPIX;
    const float* gp = gt + (size_t)b * NPIX;
    const int base = chunk * PIX_PER_BLOCK;   // contiguous 64KB regions (best map)
    const float scale = (float)BINS / BLOSS_MAX;

    float f_acc = 0.f, b_acc = 0.f;

    for (int it = 0; it < ITERS_A; ++it) {
        const int i = base + it * (TPB_A * PPT) + (tid << 2);
        const f32x4 a = *(const f32x4*)(p0 + i);
        const f32x4 c = *(const f32x4*)(p1 + i);
        const f32x4 g = *(const f32x4*)(gp + i);
        const float dv[PPT] = {c.x - a.x, c.y - a.y, c.z - a.z, c.w - a.w};
        const float gv[PPT] = {g.x, g.y, g.z, g.w};
        #pragma unroll
        for (int q = 0; q < PPT; ++q) {
            // -log(1-sigmoid(d)) = softplus(d); -log(sigmoid(d)) = softplus(d)-d
            const float d = dv[q];
            const float sp = fmaxf(d, 0.f) + __logf(1.f + __expf(-fabsf(d)));
            const bool fg = gv[q] > 0.5f;
            const float fl = fminf(sp - d, F_CAP);     // foreground loss (exact)
            const float bl = fminf(sp, B_CAP);         // background loss (exact)
            f_acc += fg ? fl : 0.f;
            b_acc += fg ? 0.f : bl;
            int bin = (int)(bl * scale);
            bin = bin < (BINS - 1) ? bin : (BINS - 1);
            // branchless: fg lanes hit a dummy word; packed u16 counter
            const int word = fg ? DUMMY_W : (bin >> 1);
            const unsigned inc = 1u << ((bin & 1) << 4);
            if constexpr (NOATOMIC) {
                // diagnostic: keep bin math alive, skip only the DS atomic
                asm volatile("" :: "v"(word), "v"(inc));
            } else {
                atomicAdd(&s_cnt[word], inc);
            }
        }
    }
    __syncthreads();

    // flush private packed histogram with plain coalesced stores (8 KB/block)
    unsigned* dst = g_hist + ((size_t)b * CHUNKS + chunk) * HBINS;
    for (int j = tid; j < HBINS; j += TPB_A) dst[j] = s_cnt[j];

    // block-reduce f_acc / b_acc -> per-block slots (no atomics)
    #pragma unroll
    for (int o = 32; o > 0; o >>= 1) {
        f_acc += __shfl_down(f_acc, o, 64);
        b_acc += __shfl_down(b_acc, o, 64);
    }
    if ((tid & 63) == 0) { s_redf[tid >> 6] = f_acc; s_redb[tid >> 6] = b_acc; }
    __syncthreads();
    if (tid == 0) {
        float f = 0.f, bs = 0.f;
        #pragma unroll
        for (int w = 0; w < TPB_A / 64; ++w) { f += s_redf[w]; bs += s_redb[w]; }
        f_part[b * CHUNKS + chunk] = f;
        b_part[b * CHUNKS + chunk] = bs;
    }
}

// One block per sample. Sums the 64 chunk histograms (bins live in registers),
// then top-k threshold via suffix scan over 256 chunks of 16 bins.
__global__ __launch_bounds__(TPB_B) void pass_b(
    const unsigned* __restrict__ g_hist, const float* __restrict__ f_part,
    const float* __restrict__ b_part, const float* __restrict__ gt_f_num,
    float* __restrict__ terms)
{
    __shared__ unsigned s_suf[TPB_B];
    __shared__ double s_wsuf[TPB_B];
    __shared__ double s_dsum;
    __shared__ double s_fb[2];

    const int b = blockIdx.x;
    const int t = threadIdx.x;

    // accumulate my 16 bins (8 packed words) across the 64 chunk histograms
    unsigned cnt[BINS_PER_CHUNK];
    #pragma unroll
    for (int j = 0; j < BINS_PER_CHUNK; ++j) cnt[j] = 0u;
    const unsigned* hb = g_hist + (size_t)b * CHUNKS * HBINS + t * WORDS_PER_THREAD;
    #pragma unroll 4
    for (int c = 0; c < CHUNKS; ++c) {
        const uint4 w0 = *(const uint4*)(hb + (size_t)c * HBINS);
        const uint4 w1 = *(const uint4*)(hb + (size_t)c * HBINS + 4);
        cnt[0]  += w0.x & 0xFFFFu;  cnt[1]  += w0.x >> 16;
        cnt[2]  += w0.y & 0xFFFFu;  cnt[3]  += w0.y >> 16;
        cnt[4]  += w0.z & 0xFFFFu;  cnt[5]  += w0.z >> 16;
        cnt[6]  += w0.w & 0xFFFFu;  cnt[7]  += w0.w >> 16;
        cnt[8]  += w1.x & 0xFFFFu;  cnt[9]  += w1.x >> 16;
        cnt[10] += w1.y & 0xFFFFu;  cnt[11] += w1.y >> 16;
        cnt[12] += w1.z & 0xFFFFu;  cnt[13] += w1.z >> 16;
        cnt[14] += w1.w & 0xFFFFu;  cnt[15] += w1.w >> 16;
    }

    // per-chunk count and midpoint-weighted sum (from registers)
    const int cb = t * BINS_PER_CHUNK;
    unsigned c = 0; double w = 0.0;
    #pragma unroll
    for (int j = 0; j < BINS_PER_CHUNK; ++j) {
        c += cnt[j];
        w += (double)cnt[j] * (double)(((float)(cb + j) + 0.5f) * BINW);
    }
    s_suf[t] = c; s_wsuf[t] = w;

    // reduce f/b per-block partials (first wave)
    if (t < 64) {   // CHUNKS == 64
        double ff = (double)f_part[b * CHUNKS + t];
        double bb = (double)b_part[b * CHUNKS + t];
        #pragma unroll
        for (int o = 32; o > 0; o >>= 1) {
            ff += __shfl_down(ff, o, 64);
            bb += __shfl_down(bb, o, 64);
        }
        if (t == 0) { s_fb[0] = ff; s_fb[1] = bb; }
    }
    __syncthreads();

    // Hillis-Steele inclusive suffix scan over 256 chunks
    for (int off = 1; off < TPB_B; off <<= 1) {
        const unsigned ac = (t + off < TPB_B) ? s_suf[t + off] : 0u;
        const double aw = (t + off < TPB_B) ? s_wsuf[t + off] : 0.0;
        __syncthreads();
        s_suf[t] += ac; s_wsuf[t] += aw;
        __syncthreads();
    }

    const long long kk = (long long)gt_f_num[b];
    const unsigned long long n_pos = (unsigned long long)s_suf[0];
    const unsigned long long suf_me = s_suf[t];
    const unsigned long long suf_nx = (t + 1 < TPB_B) ? s_suf[t + 1] : 0ull;

    if (kk > 0 && (unsigned long long)kk < n_pos &&
        suf_nx < (unsigned long long)kk && (unsigned long long)kk <= suf_me) {
        // threshold bin is in my chunk; scan its 16 bins top-down (registers)
        unsigned long long cum = suf_nx;
        double W = (t + 1 < TPB_B) ? s_wsuf[t + 1] : 0.0;
        int bstar = cb;
        for (int j = BINS_PER_CHUNK - 1; j >= 0; --j) {
            const unsigned cc = cnt[j];
            if (cum + cc >= (unsigned long long)kk) { bstar = cb + j; break; }
            cum += cc;
            W += (double)cc * (double)(((float)(cb + j) + 0.5f) * BINW);
        }
        const double partial = (double)(kk - (long long)cum);
        s_dsum = W + partial * (double)(((float)bstar + 0.5f) * BINW);
    }
    __syncthreads();

    if (t == 0) {
        const double S_total = s_fb[1];            // exact bg sum
        const double fs = s_fb[0];                 // exact fg sum
        const double gfn = (double)gt_f_num[b];
        double dsum, dnum;
        if (kk <= 0) { dsum = 0.0; dnum = 0.0; }
        else if ((unsigned long long)kk >= n_pos) { dsum = S_total; dnum = (double)n_pos; }
        else { dsum = s_dsum; dnum = (double)kk; }
        const double term = dsum / (dnum + 1e-16)
                          + fs / (gfn + 1e-16)
                          + (S_total - dsum) / ((double)NPIX + 1e-16);
        terms[b] = (float)term;
    }
}

__global__ void pass_c(const float* __restrict__ terms, float* __restrict__ out)
{
    if (threadIdx.x == 0 && blockIdx.x == 0) {
        float s = 0.f;
        #pragma unroll
        for (int i = 0; i < NB; ++i) s += terms[i];
        out[0] = s / (float)NB;
    }
}

extern "C" void kernel_launch(void* const* d_in, const int* in_sizes, int n_in,
                              void* d_out, int out_size, void* d_ws, size_t ws_size,
                              hipStream_t stream) {
    const float* probs = (const float*)d_in[0];
    const float* gt    = (const float*)d_in[1];
    const float* gfn   = (const float*)d_in[2];
    char* ws = (char*)d_ws;

    // Workspace layout:
    //   g_hist : NB*CHUNKS*HBINS u32  (8 MB)  per-block packed histograms
    //   f_part : NB*CHUNKS floats
    //   b_part : NB*CHUNKS floats
    //   terms  : NB floats
    const size_t hist_bytes = (size_t)NB * CHUNKS * HBINS * sizeof(unsigned);
    unsigned* g_hist = (unsigned*)ws;
    float*    f_part = (float*)(ws + hist_bytes);
    float*    b_part = f_part + NB * CHUNKS;
    float*    terms  = b_part + NB * CHUNKS;

    hipLaunchKernelGGL(pass_a_t<false>, dim3(NB * CHUNKS), dim3(TPB_A), 0, stream,
                       probs, gt, g_hist, f_part, b_part);
    hipLaunchKernelGGL(pass_b, dim3(NB), dim3(TPB_B), 0, stream,
                       g_hist, f_part, b_part, gfn, terms);
    hipLaunchKernelGGL(pass_c, dim3(1), dim3(64), 0, stream,
                       terms, (float*)d_out);

    // DIAGNOSTIC dispatch (after all consumers; overwrites already-consumed
    // buffers; output unused). Duration isolates the LDS-atomic cost:
    // na_dur = total - 159(fills) - pass_a - ~2.5(pass_b+c).
    hipLaunchKernelGGL(pass_a_t<true>, dim3(NB * CHUNKS), dim3(TPB_A), 0, stream,
                       probs, gt, g_hist, f_part, b_part);
}

// Round 7
// 233.988 us; speedup vs baseline: 1.2236x; 1.2236x over previous
//
#include <hip/hip_runtime.h>
#include <math.h>

// Problem constants (match reference file)
#define NB 16
#define NPIX 1048576                       // 1024*1024
#define BINS 4096
#define HBINS (BINS / 2)                   // packed u16-pair words: 2048
#define DUMMY_W HBINS                      // dead word for fg lanes (branchless atomic)
#define CHUNKS 64                          // blocks per sample in pass A
#define TPB_A 256
#define PIX_PER_BLOCK (NPIX / CHUNKS)      // 16384
#define PPT 4                              // pixels per thread per iter (one float4/stream)
#define ITERS_A (PIX_PER_BLOCK / (TPB_A * PPT))   // 16
#define TPB_B 256
#define BINS_PER_CHUNK (BINS / TPB_B)      // 16 bins per pass_b thread
#define WORDS_PER_THREAD (HBINS / TPB_B)   // 8 packed words per pass_b thread
#define BLOSS_MAX 16.2f
#define BINW (BLOSS_MAX / (float)BINS)
#define B_CAP 15.9424f                     // -log(1-(1-1e-7f)) in f32 = -log(2*2^-24)
#define F_CAP 16.1181f                     // -log(1e-7f)

typedef float f32x4 __attribute__((ext_vector_type(4)));

// Pass A: round-3/6 structure (known 81 us), ONE variable changed: the three
// input loads are NON-TEMPORAL. Zero-reuse streaming means every normal load
// allocates+tracks an L1 line-fill; measured 3.7 B/cy/CU ~= ~32 outstanding
// 64B lines x ~550cy latency = a per-CU L1 miss-queue cap (invariant to
// occupancy/structure/atomics across rounds 0-6; LDS atomic proven FREE by
// the round-6 NOATOMIC ablation; L3-resident run equally slow). Non-temporal
// loads set the cache-bypass bits -> stream from L2/L3 without L1 allocation.
__global__ __launch_bounds__(TPB_A, 8) void pass_a(
    const float* __restrict__ probs, const float* __restrict__ gt,
    unsigned* __restrict__ g_hist, float* __restrict__ f_part,
    float* __restrict__ b_part)
{
    __shared__ unsigned s_cnt[HBINS + 8];     // packed 2x u16 counts + dummy pad
    __shared__ float s_redf[TPB_A / 64];
    __shared__ float s_redb[TPB_A / 64];

    const int tid = threadIdx.x;
    for (int j = tid; j < HBINS + 8; j += TPB_A) s_cnt[j] = 0u;
    __syncthreads();

    const int blk = blockIdx.x;
    const int b = blk / CHUNKS;
    const int chunk = blk % CHUNKS;
    const float* p0 = probs + (size_t)b * 2 * NPIX;
    const float* p1 = p0 + NPIX;
    const float* gp = gt + (size_t)b * NPIX;
    const int base = chunk * PIX_PER_BLOCK;   // contiguous 64KB regions (best map)
    const float scale = (float)BINS / BLOSS_MAX;

    float f_acc = 0.f, b_acc = 0.f;

    for (int it = 0; it < ITERS_A; ++it) {
        const int i = base + it * (TPB_A * PPT) + (tid << 2);
        const f32x4 a = __builtin_nontemporal_load((const f32x4*)(p0 + i));
        const f32x4 c = __builtin_nontemporal_load((const f32x4*)(p1 + i));
        const f32x4 g = __builtin_nontemporal_load((const f32x4*)(gp + i));
        const float dv[PPT] = {c.x - a.x, c.y - a.y, c.z - a.z, c.w - a.w};
        const float gv[PPT] = {g.x, g.y, g.z, g.w};
        #pragma unroll
        for (int q = 0; q < PPT; ++q) {
            // -log(1-sigmoid(d)) = softplus(d); -log(sigmoid(d)) = softplus(d)-d
            const float d = dv[q];
            const float sp = fmaxf(d, 0.f) + __logf(1.f + __expf(-fabsf(d)));
            const bool fg = gv[q] > 0.5f;
            const float fl = fminf(sp - d, F_CAP);     // foreground loss (exact)
            const float bl = fminf(sp, B_CAP);         // background loss (exact)
            f_acc += fg ? fl : 0.f;
            b_acc += fg ? 0.f : bl;
            int bin = (int)(bl * scale);
            bin = bin < (BINS - 1) ? bin : (BINS - 1);
            // branchless: fg lanes hit a dummy word; packed u16 counter
            // (per-block bin count <= 16384, no overflow); proven ~free (r6)
            const int word = fg ? DUMMY_W : (bin >> 1);
            const unsigned inc = 1u << ((bin & 1) << 4);
            atomicAdd(&s_cnt[word], inc);
        }
    }
    __syncthreads();

    // flush private packed histogram with plain coalesced stores (8 KB/block)
    unsigned* dst = g_hist + ((size_t)b * CHUNKS + chunk) * HBINS;
    for (int j = tid; j < HBINS; j += TPB_A) dst[j] = s_cnt[j];

    // block-reduce f_acc / b_acc -> per-block slots (no atomics)
    #pragma unroll
    for (int o = 32; o > 0; o >>= 1) {
        f_acc += __shfl_down(f_acc, o, 64);
        b_acc += __shfl_down(b_acc, o, 64);
    }
    if ((tid & 63) == 0) { s_redf[tid >> 6] = f_acc; s_redb[tid >> 6] = b_acc; }
    __syncthreads();
    if (tid == 0) {
        float f = 0.f, bs = 0.f;
        #pragma unroll
        for (int w = 0; w < TPB_A / 64; ++w) { f += s_redf[w]; bs += s_redb[w]; }
        f_part[b * CHUNKS + chunk] = f;
        b_part[b * CHUNKS + chunk] = bs;
    }
}

// One block per sample. Sums the 64 chunk histograms (bins live in registers),
// then top-k threshold via suffix scan over 256 chunks of 16 bins.
__global__ __launch_bounds__(TPB_B) void pass_b(
    const unsigned* __restrict__ g_hist, const float* __restrict__ f_part,
    const float* __restrict__ b_part, const float* __restrict__ gt_f_num,
    float* __restrict__ terms)
{
    __shared__ unsigned s_suf[TPB_B];
    __shared__ double s_wsuf[TPB_B];
    __shared__ double s_dsum;
    __shared__ double s_fb[2];

    const int b = blockIdx.x;
    const int t = threadIdx.x;

    // accumulate my 16 bins (8 packed words) across the 64 chunk histograms
    unsigned cnt[BINS_PER_CHUNK];
    #pragma unroll
    for (int j = 0; j < BINS_PER_CHUNK; ++j) cnt[j] = 0u;
    const unsigned* hb = g_hist + (size_t)b * CHUNKS * HBINS + t * WORDS_PER_THREAD;
    #pragma unroll 4
    for (int c = 0; c < CHUNKS; ++c) {
        const uint4 w0 = *(const uint4*)(hb + (size_t)c * HBINS);
        const uint4 w1 = *(const uint4*)(hb + (size_t)c * HBINS + 4);
        cnt[0]  += w0.x & 0xFFFFu;  cnt[1]  += w0.x >> 16;
        cnt[2]  += w0.y & 0xFFFFu;  cnt[3]  += w0.y >> 16;
        cnt[4]  += w0.z & 0xFFFFu;  cnt[5]  += w0.z >> 16;
        cnt[6]  += w0.w & 0xFFFFu;  cnt[7]  += w0.w >> 16;
        cnt[8]  += w1.x & 0xFFFFu;  cnt[9]  += w1.x >> 16;
        cnt[10] += w1.y & 0xFFFFu;  cnt[11] += w1.y >> 16;
        cnt[12] += w1.z & 0xFFFFu;  cnt[13] += w1.z >> 16;
        cnt[14] += w1.w & 0xFFFFu;  cnt[15] += w1.w >> 16;
    }

    // per-chunk count and midpoint-weighted sum (from registers)
    const int cb = t * BINS_PER_CHUNK;
    unsigned c = 0; double w = 0.0;
    #pragma unroll
    for (int j = 0; j < BINS_PER_CHUNK; ++j) {
        c += cnt[j];
        w += (double)cnt[j] * (double)(((float)(cb + j) + 0.5f) * BINW);
    }
    s_suf[t] = c; s_wsuf[t] = w;

    // reduce f/b per-block partials (first wave)
    if (t < 64) {   // CHUNKS == 64
        double ff = (double)f_part[b * CHUNKS + t];
        double bb = (double)b_part[b * CHUNKS + t];
        #pragma unroll
        for (int o = 32; o > 0; o >>= 1) {
            ff += __shfl_down(ff, o, 64);
            bb += __shfl_down(bb, o, 64);
        }
        if (t == 0) { s_fb[0] = ff; s_fb[1] = bb; }
    }
    __syncthreads();

    // Hillis-Steele inclusive suffix scan over 256 chunks
    for (int off = 1; off < TPB_B; off <<= 1) {
        const unsigned ac = (t + off < TPB_B) ? s_suf[t + off] : 0u;
        const double aw = (t + off < TPB_B) ? s_wsuf[t + off] : 0.0;
        __syncthreads();
        s_suf[t] += ac; s_wsuf[t] += aw;
        __syncthreads();
    }

    const long long kk = (long long)gt_f_num[b];
    const unsigned long long n_pos = (unsigned long long)s_suf[0];
    const unsigned long long suf_me = s_suf[t];
    const unsigned long long suf_nx = (t + 1 < TPB_B) ? s_suf[t + 1] : 0ull;

    if (kk > 0 && (unsigned long long)kk < n_pos &&
        suf_nx < (unsigned long long)kk && (unsigned long long)kk <= suf_me) {
        // threshold bin is in my chunk; scan its 16 bins top-down (registers)
        unsigned long long cum = suf_nx;
        double W = (t + 1 < TPB_B) ? s_wsuf[t + 1] : 0.0;
        int bstar = cb;
        for (int j = BINS_PER_CHUNK - 1; j >= 0; --j) {
            const unsigned cc = cnt[j];
            if (cum + cc >= (unsigned long long)kk) { bstar = cb + j; break; }
            cum += cc;
            W += (double)cc * (double)(((float)(cb + j) + 0.5f) * BINW);
        }
        const double partial = (double)(kk - (long long)cum);
        s_dsum = W + partial * (double)(((float)bstar + 0.5f) * BINW);
    }
    __syncthreads();

    if (t == 0) {
        const double S_total = s_fb[1];            // exact bg sum
        const double fs = s_fb[0];                 // exact fg sum
        const double gfn = (double)gt_f_num[b];
        double dsum, dnum;
        if (kk <= 0) { dsum = 0.0; dnum = 0.0; }
        else if ((unsigned long long)kk >= n_pos) { dsum = S_total; dnum = (double)n_pos; }
        else { dsum = s_dsum; dnum = (double)kk; }
        const double term = dsum / (dnum + 1e-16)
                          + fs / (gfn + 1e-16)
                          + (S_total - dsum) / ((double)NPIX + 1e-16);
        terms[b] = (float)term;
    }
}

__global__ void pass_c(const float* __restrict__ terms, float* __restrict__ out)
{
    if (threadIdx.x == 0 && blockIdx.x == 0) {
        float s = 0.f;
        #pragma unroll
        for (int i = 0; i < NB; ++i) s += terms[i];
        out[0] = s / (float)NB;
    }
}

extern "C" void kernel_launch(void* const* d_in, const int* in_sizes, int n_in,
                              void* d_out, int out_size, void* d_ws, size_t ws_size,
                              hipStream_t stream) {
    const float* probs = (const float*)d_in[0];
    const float* gt    = (const float*)d_in[1];
    const float* gfn   = (const float*)d_in[2];
    char* ws = (char*)d_ws;

    // Workspace layout:
    //   g_hist : NB*CHUNKS*HBINS u32  (8 MB)  per-block packed histograms
    //   f_part : NB*CHUNKS floats
    //   b_part : NB*CHUNKS floats
    //   terms  : NB floats
    const size_t hist_bytes = (size_t)NB * CHUNKS * HBINS * sizeof(unsigned);
    unsigned* g_hist = (unsigned*)ws;
    float*    f_part = (float*)(ws + hist_bytes);
    float*    b_part = f_part + NB * CHUNKS;
    float*    terms  = b_part + NB * CHUNKS;

    hipLaunchKernelGGL(pass_a, dim3(NB * CHUNKS), dim3(TPB_A), 0, stream,
                       probs, gt, g_hist, f_part, b_part);
    hipLaunchKernelGGL(pass_b, dim3(NB), dim3(TPB_B), 0, stream,
                       g_hist, f_part, b_part, gfn, terms);
    hipLaunchKernelGGL(pass_c, dim3(1), dim3(64), 0, stream,
                       terms, (float*)d_out);
}